// Round 11
// baseline (326.699 us; speedup 1.0000x reference)
//
#include <hip/hip_runtime.h>
#include <hip/hip_bf16.h>
#include <cstdint>
#include <cstddef>

#define BLK 256     // pack/final block size
#define DG 12
#define CTILES 32   // tiles per chunk (LDS stage = CTILES*16 pairs * 32 B = 16 KB)

static constexpr float EPS_ = 0.01f;
// exp(-d/sigma) = exp2(C2*d), C2 = -1/(sigma*ln2), sigma=2.5; C2SQ = C2^2
static constexpr float C2SQ_ = 0.333019070232236f;

typedef __attribute__((ext_vector_type(2))) float v2f;   // packed fp32 (VOP3P)
typedef __attribute__((ext_vector_type(8))) short v8s;   // 8 bf16 (MFMA A/B frag)
typedef __attribute__((ext_vector_type(4))) float v4f;   // MFMA C/D frag

// ---------------------------------------------------------------------------
// Kernel 0: pack (side-major streams) + init accumulators. P = point pairs.
//  pk1s[side*P+pr] -> {x0,x1,y0,y1},{z0,z1,h0,h1}  h=|p|^2/2  (argmin)
//  pkps[side*P+pr] -> {x0,x1,y0,y1},{z0,z1,h0,h1}  h=C2SQ*|p|^2 (RBF, prescaled)
//  fpk[side][tile][lane] -> int4 B-frag of F=[s_x(12),1.0] bf16
//  red[26L]=0, keys[2L]=~0 (ws is 0xAA-poisoned; min-keys need ~0).
// Pads (n>=N): pos 1e9, h huge (argmin never wins; w==0), F=0.
// ---------------------------------------------------------------------------
__global__ __launch_bounds__(BLK) void pip_pack(
    const float* __restrict__ g1_pos, const float* __restrict__ g2_pos,
    const float* __restrict__ s1_v,   const float* __restrict__ s1_x,
    const float* __restrict__ s2_v,   const float* __restrict__ s2_x,
    float4* __restrict__ pk1s, float4* __restrict__ pkps, int4* __restrict__ fpk,
    float* __restrict__ red, unsigned long long* __restrict__ keys,
    int N, int T, int L)
{
#pragma clang fp contract(off)
    const int P = T * 16;
    const int tid = blockIdx.x * BLK + threadIdx.x;

    // ---- init accumulators (merged to save a launch)
    if (tid < 26 * L) red[tid] = 0.f;
    else if (tid < 28 * L) keys[tid - 26 * L] = ~0ull;

    // ---- pack tasks
    if (tid < 2 * P) {                         // pk1s: tid = side*P + pr
        const int side = tid / P;
        const int pr = tid - side * P;
        const float* src = side ? g2_pos : g1_pos;
        const int n0 = 2 * pr, n1 = 2 * pr + 1;
        float x0 = 1e9f, y0 = 1e9f, z0 = 1e9f, h0 = 1.5e18f;
        float x1 = 1e9f, y1 = 1e9f, z1 = 1e9f, h1 = 1.5e18f;
        if (n0 < N) {
            x0 = src[3 * n0]; y0 = src[3 * n0 + 1]; z0 = src[3 * n0 + 2];
            h0 = 0.5f * ((x0 * x0 + y0 * y0) + z0 * z0);   // exact half of ref |p|^2
        }
        if (n1 < N) {
            x1 = src[3 * n1]; y1 = src[3 * n1 + 1]; z1 = src[3 * n1 + 2];
            h1 = 0.5f * ((x1 * x1 + y1 * y1) + z1 * z1);
        }
        pk1s[(size_t)tid * 2 + 0] = make_float4(x0, x1, y0, y1);
        pk1s[(size_t)tid * 2 + 1] = make_float4(z0, z1, h0, h1);
    } else if (tid < 4 * P) {                  // pkps: u = side*P + pr
        const int u = tid - 2 * P;
        const int side = u / P;
        const int pr = u - side * P;
        const float* src = side ? s2_v : s1_v;
        const int n0 = 2 * pr, n1 = 2 * pr + 1;
        float x0 = 1e9f, y0 = 1e9f, z0 = 1e9f, h0 = 1e18f;
        float x1 = 1e9f, y1 = 1e9f, z1 = 1e9f, h1 = 1e18f;
        if (n0 < N) {
            x0 = src[3 * n0]; y0 = src[3 * n0 + 1]; z0 = src[3 * n0 + 2];
            h0 = C2SQ_ * ((x0 * x0 + y0 * y0) + z0 * z0);  // prescaled |p|^2
        }
        if (n1 < N) {
            x1 = src[3 * n1]; y1 = src[3 * n1 + 1]; z1 = src[3 * n1 + 2];
            h1 = C2SQ_ * ((x1 * x1 + y1 * y1) + z1 * z1);
        }
        pkps[(size_t)u * 2 + 0] = make_float4(x0, x1, y0, y1);
        pkps[(size_t)u * 2 + 1] = make_float4(z0, z1, h0, h1);
    } else {                                   // fpk B-fragments
        const int u = tid - 4 * P;
        if (u < 128 * T) {
            const int side = u / (64 * T);
            const int r = u - side * 64 * T;
            const int t = r >> 6;
            const int ln = r & 63;
            const float* X = side ? s2_x : s1_x;
            const int nb = 32 * t + ((ln >> 4) << 3);
            const int feat = ln & 15;
            int w[4];
#pragma unroll
            for (int d = 0; d < 4; ++d) {
                const int n0 = nb + 2 * d, n1 = nb + 2 * d + 1;
                const float f0 = (n0 < N) ? (feat < 12 ? X[(size_t)n0 * DG + feat] : (feat == 12 ? 1.f : 0.f)) : 0.f;
                const float f1 = (n1 < N) ? (feat < 12 ? X[(size_t)n1 * DG + feat] : (feat == 12 ? 1.f : 0.f)) : 0.f;
                __hip_bfloat162 h = __float22bfloat162_rn(make_float2(f0, f1));
                __builtin_memcpy(&w[d], &h, 4);
            }
            fpk[((size_t)side * T + t) * 64 + ln] = make_int4(w[0], w[1], w[2], w[3]);
        }
    }
}

// ---------------------------------------------------------------------------
// Kernel 1: partial scans, side-split, dp-interleaved, LDS-staged argmin.
// Block = 128 thr = 2 waves, one side (blockIdx.z), one chunk (blockIdx.y).
// The chunk's argmin stream (16 KB) is staged into LDS once per block, so the
// hot loop's argmin reads are ds_read_b128 (fine-grained lgkmcnt, broadcast,
// no bank conflicts) instead of SMEM loads that force lgkmcnt(0) drains.
// Argmin: packed fp32 half-scale — bit-identical ordering to the reference's
// |q|^2+|p|^2-2q.p fp32 formula. RBF: prescaled dot-form t=C2SQ*d2 (clamped),
// w = exp2(-sqrt(t)); bf16 pack via 1-inst v_perm truncation.
// Results accumulate via device atomics into red/keys.
// ---------------------------------------------------------------------------
__global__ __launch_bounds__(128, 5) void pip_partial(
    const float* __restrict__ locs_l, const float* __restrict__ locs_r,
    const float4* __restrict__ pk1s,  const float4* __restrict__ pkps,
    const int4* __restrict__ fpk,
    float* __restrict__ red, unsigned long long* __restrict__ keys,
    int L, int T, int P)
{
#pragma clang fp contract(off)   // plain mul/add unfused; fma only where written
    __shared__ float4 sPK[CTILES * 32];   // {XY,ZH} interleaved per pair, 16 KB

    const int lane = threadIdx.x & 63;
    const int wv = threadIdx.x >> 6;
    const int side = blockIdx.z;
    const int qbase = blockIdx.x * 128 + wv * 64;
    const int lq = qbase + lane;          // this lane's argmin query (L % 128 == 0)

    const float* __restrict__ locs = side ? locs_r : locs_l;

    const float4* __restrict__ pk1b = pk1s + (size_t)side * P * 2;
    const float4* __restrict__ pkpb = pkps + (size_t)side * P * 2;

    const int t0 = blockIdx.y * CTILES;
    const int t1 = (t0 + CTILES < T) ? (t0 + CTILES) : T;
    const int nQuads = (t1 - t0) * 32;    // float4 count to stage

    // ---- stage this chunk's argmin stream into LDS (once per block)
    {
        const float4* src = pk1b + (size_t)t0 * 32;
        for (int i = threadIdx.x; i < nQuads; i += 128)
            sPK[i] = src[i];
    }

    // argmin query data (half-scale |q|^2) — overlaps with staging loads
    const float qx = locs[3 * lq + 0];
    const float qy = locs[3 * lq + 1];
    const float qz = locs[3 * lq + 2];
    const float nqh = 0.5f * ((qx * qx + qy * qy) + qz * qz);
    const v2f qx2 = {qx, qx}, qy2 = {qy, qy}, qz2 = {qz, qz};

    // RBF fragment-role queries: q = qbase + 16*mt + (lane&15); prescaled consts
    float nq2[4], m2x[4], m2y[4], m2z[4];
#pragma unroll
    for (int mt = 0; mt < 4; ++mt) {
        const int qm = qbase + 16 * mt + (lane & 15);
        const float a = locs[3 * qm + 0];
        const float b = locs[3 * qm + 1];
        const float c = locs[3 * qm + 2];
        nq2[mt] = C2SQ_ * ((a * a + b * b) + c * c);
        const float s2 = -2.0f * C2SQ_;
        m2x[mt] = s2 * a; m2y[mt] = s2 * b; m2z[mt] = s2 * c;
    }

    v4f cC[4];
#pragma unroll
    for (int mt = 0; mt < 4; ++mt) cC[mt] = (v4f)0.f;

    float bd = 3.4e38f;
    unsigned bi = 0u;

    __syncthreads();   // staging complete

    for (int tg = t0; tg < t1; ++tg) {
        const v8s b = ((const v8s*)fpk)[((size_t)side * T + tg) * 64 + lane];  // used at tile end
        union AF { int i[4]; v8s s; };
        AF af[4];
        const int prb = tg * 16;
        const int tl = (tg - t0) * 32;              // LDS float4 base of this tile
        const int pg0 = prb + ((lane >> 4) << 2);   // this lane's 4 point-pairs

#pragma unroll
        for (int dp = 0; dp < 4; ++dp) {
            // ---- issue this group's RBF loads (latency hidden by argmin below)
            const float4 FXY = pkpb[(size_t)(pg0 + dp) * 2 + 0];
            const float4 FZH = pkpb[(size_t)(pg0 + dp) * 2 + 1];

            // ---- argmin: 4 packed-pair iterations from LDS (broadcast reads)
#pragma unroll
            for (int jj = 0; jj < 4; ++jj) {
                const int j = 4 * dp + jj;
                const float4 XY = sPK[tl + 2 * j + 0];
                const float4 ZH = sPK[tl + 2 * j + 1];
                const v2f xx = {XY.x, XY.y}, yy = {XY.z, XY.w};
                const v2f zz = {ZH.x, ZH.y}, hh = {ZH.z, ZH.w};
                const v2f dot = __builtin_elementwise_fma(qz2, zz,
                                  __builtin_elementwise_fma(qy2, yy, qx2 * xx));
                const v2f d2 = (nqh + hh) - dot;   // d2/2; ordering == ref
                const bool c0 = d2.x < bd;
                bd = c0 ? d2.x : bd;
                bi = c0 ? (unsigned)(2 * (prb + j)) : bi;
                const bool c1 = d2.y < bd;
                bd = c1 ? d2.y : bd;
                bi = c1 ? (unsigned)(2 * (prb + j) + 1) : bi;
            }

            // ---- RBF for this group: prescaled dot-form distance
            const v2f px = {FXY.x, FXY.y}, py = {FXY.z, FXY.w};
            const v2f pz = {FZH.x, FZH.y}, ph = {FZH.z, FZH.w};
#pragma unroll
            for (int mt = 0; mt < 4; ++mt) {
                const v2f mx = {m2x[mt], m2x[mt]};
                const v2f my = {m2y[mt], m2y[mt]};
                const v2f mz = {m2z[mt], m2z[mt]};
                const v2f s  = nq2[mt] + ph;
                v2f t = __builtin_elementwise_fma(mz, pz,
                          __builtin_elementwise_fma(my, py,
                            __builtin_elementwise_fma(mx, px, s)));
                t = __builtin_elementwise_max(t, (v2f)0.f);   // cancellation guard
                const float w0 = __builtin_amdgcn_exp2f(-__builtin_amdgcn_sqrtf(t.x));
                const float w1 = __builtin_amdgcn_exp2f(-__builtin_amdgcn_sqrtf(t.y));
                // 1-inst bf16x2 pack (truncation): {hi16(w1), hi16(w0)}
                af[mt].i[dp] = (int)__builtin_amdgcn_perm(
                    __float_as_uint(w1), __float_as_uint(w0), 0x07060302u);
            }
        }

        // ---- 4 MFMAs
#pragma unroll
        for (int mt = 0; mt < 4; ++mt)
            cC[mt] = __builtin_amdgcn_mfma_f32_16x16x32_bf16(af[mt].s, b, cC[mt], 0, 0, 0);
    }

    // ---- accumulate into red/keys with device atomics
    const int feat = lane & 15;
    if (feat < 13) {
        const int slot = side * 13 + feat;
        // C/D layout: col(=feat)=lane&15, row(=q within 16-tile)=(lane>>4)*4+reg
#pragma unroll
        for (int mt = 0; mt < 4; ++mt)
#pragma unroll
            for (int r = 0; r < 4; ++r) {
                const int q = qbase + 16 * mt + ((lane >> 4) << 2) + r;
                atomicAdd(&red[(size_t)slot * L + q], cC[mt][r]);
            }
    }
    const unsigned long long key =
        ((unsigned long long)__float_as_uint(bd) << 32) | (unsigned long long)bi;
    atomicMin(&keys[(size_t)side * L + lq], key);   // d2h > 0 -> bit-ordered
}

__device__ __forceinline__ float tanh_pos(float x) {
    const float t = __expf(-2.f * x);
    return (1.f - t) / (1.f + t);
}

// ---------------------------------------------------------------------------
// Kernel 2: gather nearest-node feats + 50->50->1 MLP. Thread = one query l.
// ---------------------------------------------------------------------------
__global__ __launch_bounds__(BLK) void pip_final(
    const float* __restrict__ red, const unsigned long long* __restrict__ keys,
    const float* __restrict__ g1_x, const float* __restrict__ g2_x,
    const float* __restrict__ W1, const float* __restrict__ b1,
    const float* __restrict__ W2, const float* __restrict__ b2,
    float* __restrict__ out, int L)
{
#pragma clang fp contract(off)
    const int l = blockIdx.x * BLK + threadIdx.x;
    if (l >= L) return;

    const unsigned idxL = (unsigned)(keys[l] & 0xffffffffull);
    const unsigned idxR = (unsigned)(keys[(size_t)L + l] & 0xffffffffull);
    const float normL = red[(size_t)12 * L + (size_t)l] + EPS_;
    const float normR = red[(size_t)25 * L + (size_t)l] + EPS_;

    float x[50];
    {
        const float4* f = (const float4*)(g1_x + (size_t)idxL * DG);
        const float4 f0 = f[0], f1 = f[1], f2 = f[2];
        x[0] = f0.x; x[1] = f0.y; x[2]  = f0.z; x[3]  = f0.w;
        x[4] = f1.x; x[5] = f1.y; x[6]  = f1.z; x[7]  = f1.w;
        x[8] = f2.x; x[9] = f2.y; x[10] = f2.z; x[11] = f2.w;
    }
#pragma unroll
    for (int k = 0; k < DG; ++k) x[12 + k] = red[(size_t)k * L + (size_t)l] / normL;
    x[24] = tanh_pos(normL);
    {
        const float4* f = (const float4*)(g2_x + (size_t)idxR * DG);
        const float4 f0 = f[0], f1 = f[1], f2 = f[2];
        x[25] = f0.x; x[26] = f0.y; x[27] = f0.z; x[28] = f0.w;
        x[29] = f1.x; x[30] = f1.y; x[31] = f1.z; x[32] = f1.w;
        x[33] = f2.x; x[34] = f2.y; x[35] = f2.z; x[36] = f2.w;
    }
#pragma unroll
    for (int k = 0; k < DG; ++k) x[37 + k] = red[(size_t)(13 + k) * L + (size_t)l] / normR;
    x[49] = tanh_pos(normR);

    float h[50];
#pragma unroll
    for (int j = 0; j < 50; ++j) h[j] = b1[j];
#pragma unroll
    for (int k = 0; k < 50; ++k) {
        const float xk = x[k];
#pragma unroll
        for (int j = 0; j < 50; ++j) h[j] = fmaf(xk, W1[k * 50 + j], h[j]);
    }
    float o = b2[0];
#pragma unroll
    for (int j = 0; j < 50; ++j) o = fmaf(fmaxf(h[j], 0.f), W2[j], o);
    out[l] = o;
}

// ---------------------------------------------------------------------------
extern "C" void kernel_launch(void* const* d_in, const int* in_sizes, int n_in,
                              void* d_out, int out_size, void* d_ws, size_t ws_size,
                              hipStream_t stream) {
    const float* locs_l = (const float*)d_in[0];
    const float* locs_r = (const float*)d_in[1];
    const float* g1_pos = (const float*)d_in[2];
    const float* g1_x   = (const float*)d_in[3];
    const float* g2_pos = (const float*)d_in[4];
    const float* g2_x   = (const float*)d_in[5];
    const float* s1_v   = (const float*)d_in[6];
    const float* s1_x   = (const float*)d_in[7];
    const float* s2_v   = (const float*)d_in[8];
    const float* s2_x   = (const float*)d_in[9];
    const float* W1     = (const float*)d_in[10];
    const float* b1     = (const float*)d_in[11];
    const float* W2     = (const float*)d_in[12];
    const float* b2     = (const float*)d_in[13];
    float* out = (float*)d_out;
    float* ws  = (float*)d_ws;

    const int L = in_sizes[0] / 3;   // 4096
    const int N = in_sizes[2] / 3;   // 40000
    const int T = (N + 31) / 32;     // 32-point tiles (1250, exact)
    const int P = T * 16;            // point pairs

    // ws layout (floats): [pk1s: 256T][pkps: 256T][fpk: 512T][red: 26L][keys: 2L u64]
    const size_t o_pkps = (size_t)256 * T;
    const size_t o_fpk  = (size_t)512 * T;
    const size_t o_red  = (size_t)1024 * T;

    const int SC = (T + CTILES - 1) / CTILES;   // 40 chunks -> grid 32 x 40 x 2

    float4* pk1s = (float4*)ws;
    float4* pkps = (float4*)(ws + o_pkps);
    int4*   fpk  = (int4*)(ws + o_fpk);
    float*  red  = ws + o_red;
    unsigned long long* keys = (unsigned long long*)(red + (size_t)26 * L);

    const int ptasks = 192 * T;              // 4P + 128T, P = 16T  (> 28L)
    pip_pack<<<dim3((ptasks + BLK - 1) / BLK), dim3(BLK), 0, stream>>>(
        g1_pos, g2_pos, s1_v, s1_x, s2_v, s2_x, pk1s, pkps, fpk, red, keys, N, T, L);

    pip_partial<<<dim3(L / 128, SC, 2), dim3(128), 0, stream>>>(
        locs_l, locs_r, pk1s, pkps, fpk, red, keys, L, T, P);

    pip_final<<<dim3((L + BLK - 1) / BLK), dim3(BLK), 0, stream>>>(
        red, keys, g1_x, g2_x, W1, b1, W2, b2, out, L);
}

// Round 12
// 303.071 us; speedup vs baseline: 1.0780x; 1.0780x over previous
//
#include <hip/hip_runtime.h>
#include <hip/hip_bf16.h>
#include <cstdint>
#include <cstddef>

#define BLK 256     // pack/final block size
#define DG 12

static constexpr float EPS_ = 0.01f;
// exp(-d/sigma) = exp2(C2*d), C2 = -1/(sigma*ln2), sigma=2.5; C2SQ = C2^2
static constexpr float C2SQ_ = 0.333019070232236f;

typedef __attribute__((ext_vector_type(2))) float v2f;   // packed fp32 (VOP3P)
typedef __attribute__((ext_vector_type(8))) short v8s;   // 8 bf16 (MFMA A/B frag)
typedef __attribute__((ext_vector_type(4))) float v4f;   // MFMA C/D frag

// ---------------------------------------------------------------------------
// Kernel 0: pack (side-major streams) + init accumulators. P = point pairs.
//  pk1s[side*P+pr] -> {x0,x1,y0,y1},{z0,z1,h0,h1}  h=|p|^2/2  (argmin, uniform)
//  pkps[side*P+pr] -> {x0,x1,y0,y1},{z0,z1,h0,h1}  h=C2SQ*|p|^2 (RBF, prescaled)
//  fpk[side][tile][lane] -> int4 B-frag of F=[s_x(12),1.0] bf16
//  red[26L]=0, keys[2L]=~0 (ws is 0xAA-poisoned; min-keys need ~0).
// Pads (n>=N): pos 1e9, h huge (argmin never wins; w==0), F=0.
// ---------------------------------------------------------------------------
__global__ __launch_bounds__(BLK) void pip_pack(
    const float* __restrict__ g1_pos, const float* __restrict__ g2_pos,
    const float* __restrict__ s1_v,   const float* __restrict__ s1_x,
    const float* __restrict__ s2_v,   const float* __restrict__ s2_x,
    float4* __restrict__ pk1s, float4* __restrict__ pkps, int4* __restrict__ fpk,
    float* __restrict__ red, unsigned long long* __restrict__ keys,
    int N, int T, int L)
{
#pragma clang fp contract(off)
    const int P = T * 16;
    const int tid = blockIdx.x * BLK + threadIdx.x;

    // ---- init accumulators (merged to save a launch)
    if (tid < 26 * L) red[tid] = 0.f;
    else if (tid < 28 * L) keys[tid - 26 * L] = ~0ull;

    // ---- pack tasks
    if (tid < 2 * P) {                         // pk1s: tid = side*P + pr
        const int side = tid / P;
        const int pr = tid - side * P;
        const float* src = side ? g2_pos : g1_pos;
        const int n0 = 2 * pr, n1 = 2 * pr + 1;
        float x0 = 1e9f, y0 = 1e9f, z0 = 1e9f, h0 = 1.5e18f;
        float x1 = 1e9f, y1 = 1e9f, z1 = 1e9f, h1 = 1.5e18f;
        if (n0 < N) {
            x0 = src[3 * n0]; y0 = src[3 * n0 + 1]; z0 = src[3 * n0 + 2];
            h0 = 0.5f * ((x0 * x0 + y0 * y0) + z0 * z0);   // exact half of ref |p|^2
        }
        if (n1 < N) {
            x1 = src[3 * n1]; y1 = src[3 * n1 + 1]; z1 = src[3 * n1 + 2];
            h1 = 0.5f * ((x1 * x1 + y1 * y1) + z1 * z1);
        }
        pk1s[(size_t)tid * 2 + 0] = make_float4(x0, x1, y0, y1);
        pk1s[(size_t)tid * 2 + 1] = make_float4(z0, z1, h0, h1);
    } else if (tid < 4 * P) {                  // pkps: u = side*P + pr
        const int u = tid - 2 * P;
        const int side = u / P;
        const int pr = u - side * P;
        const float* src = side ? s2_v : s1_v;
        const int n0 = 2 * pr, n1 = 2 * pr + 1;
        float x0 = 1e9f, y0 = 1e9f, z0 = 1e9f, h0 = 1e18f;
        float x1 = 1e9f, y1 = 1e9f, z1 = 1e9f, h1 = 1e18f;
        if (n0 < N) {
            x0 = src[3 * n0]; y0 = src[3 * n0 + 1]; z0 = src[3 * n0 + 2];
            h0 = C2SQ_ * ((x0 * x0 + y0 * y0) + z0 * z0);  // prescaled |p|^2
        }
        if (n1 < N) {
            x1 = src[3 * n1]; y1 = src[3 * n1 + 1]; z1 = src[3 * n1 + 2];
            h1 = C2SQ_ * ((x1 * x1 + y1 * y1) + z1 * z1);
        }
        pkps[(size_t)u * 2 + 0] = make_float4(x0, x1, y0, y1);
        pkps[(size_t)u * 2 + 1] = make_float4(z0, z1, h0, h1);
    } else {                                   // fpk B-fragments
        const int u = tid - 4 * P;
        if (u < 128 * T) {
            const int side = u / (64 * T);
            const int r = u - side * 64 * T;
            const int t = r >> 6;
            const int ln = r & 63;
            const float* X = side ? s2_x : s1_x;
            const int nb = 32 * t + ((ln >> 4) << 3);
            const int feat = ln & 15;
            int w[4];
#pragma unroll
            for (int d = 0; d < 4; ++d) {
                const int n0 = nb + 2 * d, n1 = nb + 2 * d + 1;
                const float f0 = (n0 < N) ? (feat < 12 ? X[(size_t)n0 * DG + feat] : (feat == 12 ? 1.f : 0.f)) : 0.f;
                const float f1 = (n1 < N) ? (feat < 12 ? X[(size_t)n1 * DG + feat] : (feat == 12 ? 1.f : 0.f)) : 0.f;
                __hip_bfloat162 h = __float22bfloat162_rn(make_float2(f0, f1));
                __builtin_memcpy(&w[d], &h, 4);
            }
            fpk[((size_t)side * T + t) * 64 + ln] = make_int4(w[0], w[1], w[2], w[3]);
        }
    }
}

// ---------------------------------------------------------------------------
// Kernel 1: partial scans, side-split, dp-interleaved, tile-loop unrolled x2.
// Block = 128 thr = 2 waves; one side per block (blockIdx.z). R10 structure
// (uniform s_load argmin stream — LDS staging regressed in R11; scalar cache
// is the cheapest broadcast transport). The x2 tile unroll gives the post-RA
// scheduler two independent tile bodies to interleave, hiding the per-tile
// first-use s_waitcnt stall that capped R10 at 63% VALUBusy.
// Argmin: packed fp32 half-scale — bit-identical ordering to the reference's
// |q|^2+|p|^2-2q.p fp32 formula. RBF: prescaled dot-form t=C2SQ*d2 (clamped),
// w = exp2(-sqrt(t)); bf16 pack via 1-inst v_perm truncation.
// Results accumulate via device atomics into red/keys.
// ---------------------------------------------------------------------------
__global__ __launch_bounds__(128, 4) void pip_partial(
    const float* __restrict__ locs_l, const float* __restrict__ locs_r,
    const float4* __restrict__ pk1s,  const float4* __restrict__ pkps,
    const int4* __restrict__ fpk,
    float* __restrict__ red, unsigned long long* __restrict__ keys,
    int L, int T, int CT, int P)
{
#pragma clang fp contract(off)   // plain mul/add unfused; fma only where written
    const int lane = threadIdx.x & 63;
    const int wv = threadIdx.x >> 6;
    const int side = blockIdx.z;
    const int qbase = blockIdx.x * 128 + wv * 64;
    const int lq = qbase + lane;          // this lane's argmin query (L % 128 == 0)

    const float* __restrict__ locs = side ? locs_r : locs_l;

    // argmin query data (half-scale |q|^2)
    const float qx = locs[3 * lq + 0];
    const float qy = locs[3 * lq + 1];
    const float qz = locs[3 * lq + 2];
    const float nqh = 0.5f * ((qx * qx + qy * qy) + qz * qz);
    const v2f qx2 = {qx, qx}, qy2 = {qy, qy}, qz2 = {qz, qz};

    // RBF fragment-role queries: q = qbase + 16*mt + (lane&15); prescaled consts
    float nq2[4], m2x[4], m2y[4], m2z[4];
#pragma unroll
    for (int mt = 0; mt < 4; ++mt) {
        const int qm = qbase + 16 * mt + (lane & 15);
        const float a = locs[3 * qm + 0];
        const float b = locs[3 * qm + 1];
        const float c = locs[3 * qm + 2];
        nq2[mt] = C2SQ_ * ((a * a + b * b) + c * c);
        const float s2 = -2.0f * C2SQ_;
        m2x[mt] = s2 * a; m2y[mt] = s2 * b; m2z[mt] = s2 * c;
    }

    v4f cC[4];
#pragma unroll
    for (int mt = 0; mt < 4; ++mt) cC[mt] = (v4f)0.f;

    float bd = 3.4e38f;
    unsigned bi = 0u;

    const float4* __restrict__ pk1b = pk1s + (size_t)side * P * 2;
    const float4* __restrict__ pkpb = pkps + (size_t)side * P * 2;

    const int t0 = blockIdx.y * CT;
    const int t1 = (t0 + CT < T) ? (t0 + CT) : T;

#pragma unroll 2
    for (int tg = t0; tg < t1; ++tg) {
        const v8s b = ((const v8s*)fpk)[((size_t)side * T + tg) * 64 + lane];  // used at tile end
        union AF { int i[4]; v8s s; };
        AF af[4];
        const int prb = tg * 16;
        const int pg0 = prb + ((lane >> 4) << 2);   // this lane's 4 point-pairs

#pragma unroll
        for (int dp = 0; dp < 4; ++dp) {
            // ---- issue this group's RBF loads (latency hidden by argmin below)
            const float4 FXY = pkpb[(size_t)(pg0 + dp) * 2 + 0];
            const float4 FZH = pkpb[(size_t)(pg0 + dp) * 2 + 1];

            // ---- argmin: 4 packed-pair iterations (uniform -> scalar loads)
#pragma unroll
            for (int jj = 0; jj < 4; ++jj) {
                const int j = 4 * dp + jj;
                const float4 XY = pk1b[(size_t)(prb + j) * 2 + 0];
                const float4 ZH = pk1b[(size_t)(prb + j) * 2 + 1];
                const v2f xx = {XY.x, XY.y}, yy = {XY.z, XY.w};
                const v2f zz = {ZH.x, ZH.y}, hh = {ZH.z, ZH.w};
                const v2f dot = __builtin_elementwise_fma(qz2, zz,
                                  __builtin_elementwise_fma(qy2, yy, qx2 * xx));
                const v2f d2 = (nqh + hh) - dot;   // d2/2; ordering == ref
                const bool c0 = d2.x < bd;
                bd = c0 ? d2.x : bd;
                bi = c0 ? (unsigned)(2 * (prb + j)) : bi;
                const bool c1 = d2.y < bd;
                bd = c1 ? d2.y : bd;
                bi = c1 ? (unsigned)(2 * (prb + j) + 1) : bi;
            }

            // ---- RBF for this group: prescaled dot-form distance
            const v2f px = {FXY.x, FXY.y}, py = {FXY.z, FXY.w};
            const v2f pz = {FZH.x, FZH.y}, ph = {FZH.z, FZH.w};
#pragma unroll
            for (int mt = 0; mt < 4; ++mt) {
                const v2f mx = {m2x[mt], m2x[mt]};
                const v2f my = {m2y[mt], m2y[mt]};
                const v2f mz = {m2z[mt], m2z[mt]};
                const v2f s  = nq2[mt] + ph;
                v2f t = __builtin_elementwise_fma(mz, pz,
                          __builtin_elementwise_fma(my, py,
                            __builtin_elementwise_fma(mx, px, s)));
                t = __builtin_elementwise_max(t, (v2f)0.f);   // cancellation guard
                const float w0 = __builtin_amdgcn_exp2f(-__builtin_amdgcn_sqrtf(t.x));
                const float w1 = __builtin_amdgcn_exp2f(-__builtin_amdgcn_sqrtf(t.y));
                // 1-inst bf16x2 pack (truncation): {hi16(w1), hi16(w0)}
                af[mt].i[dp] = (int)__builtin_amdgcn_perm(
                    __float_as_uint(w1), __float_as_uint(w0), 0x07060302u);
            }
        }

        // ---- 4 MFMAs
#pragma unroll
        for (int mt = 0; mt < 4; ++mt)
            cC[mt] = __builtin_amdgcn_mfma_f32_16x16x32_bf16(af[mt].s, b, cC[mt], 0, 0, 0);
    }

    // ---- accumulate into red/keys with device atomics
    const int feat = lane & 15;
    if (feat < 13) {
        const int slot = side * 13 + feat;
        // C/D layout: col(=feat)=lane&15, row(=q within 16-tile)=(lane>>4)*4+reg
#pragma unroll
        for (int mt = 0; mt < 4; ++mt)
#pragma unroll
            for (int r = 0; r < 4; ++r) {
                const int q = qbase + 16 * mt + ((lane >> 4) << 2) + r;
                atomicAdd(&red[(size_t)slot * L + q], cC[mt][r]);
            }
    }
    const unsigned long long key =
        ((unsigned long long)__float_as_uint(bd) << 32) | (unsigned long long)bi;
    atomicMin(&keys[(size_t)side * L + lq], key);   // d2h > 0 -> bit-ordered
}

__device__ __forceinline__ float tanh_pos(float x) {
    const float t = __expf(-2.f * x);
    return (1.f - t) / (1.f + t);
}

// ---------------------------------------------------------------------------
// Kernel 2: gather nearest-node feats + 50->50->1 MLP. Thread = one query l.
// ---------------------------------------------------------------------------
__global__ __launch_bounds__(BLK) void pip_final(
    const float* __restrict__ red, const unsigned long long* __restrict__ keys,
    const float* __restrict__ g1_x, const float* __restrict__ g2_x,
    const float* __restrict__ W1, const float* __restrict__ b1,
    const float* __restrict__ W2, const float* __restrict__ b2,
    float* __restrict__ out, int L)
{
#pragma clang fp contract(off)
    const int l = blockIdx.x * BLK + threadIdx.x;
    if (l >= L) return;

    const unsigned idxL = (unsigned)(keys[l] & 0xffffffffull);
    const unsigned idxR = (unsigned)(keys[(size_t)L + l] & 0xffffffffull);
    const float normL = red[(size_t)12 * L + (size_t)l] + EPS_;
    const float normR = red[(size_t)25 * L + (size_t)l] + EPS_;

    float x[50];
    {
        const float4* f = (const float4*)(g1_x + (size_t)idxL * DG);
        const float4 f0 = f[0], f1 = f[1], f2 = f[2];
        x[0] = f0.x; x[1] = f0.y; x[2]  = f0.z; x[3]  = f0.w;
        x[4] = f1.x; x[5] = f1.y; x[6]  = f1.z; x[7]  = f1.w;
        x[8] = f2.x; x[9] = f2.y; x[10] = f2.z; x[11] = f2.w;
    }
#pragma unroll
    for (int k = 0; k < DG; ++k) x[12 + k] = red[(size_t)k * L + (size_t)l] / normL;
    x[24] = tanh_pos(normL);
    {
        const float4* f = (const float4*)(g2_x + (size_t)idxR * DG);
        const float4 f0 = f[0], f1 = f[1], f2 = f[2];
        x[25] = f0.x; x[26] = f0.y; x[27] = f0.z; x[28] = f0.w;
        x[29] = f1.x; x[30] = f1.y; x[31] = f1.z; x[32] = f1.w;
        x[33] = f2.x; x[34] = f2.y; x[35] = f2.z; x[36] = f2.w;
    }
#pragma unroll
    for (int k = 0; k < DG; ++k) x[37 + k] = red[(size_t)(13 + k) * L + (size_t)l] / normR;
    x[49] = tanh_pos(normR);

    float h[50];
#pragma unroll
    for (int j = 0; j < 50; ++j) h[j] = b1[j];
#pragma unroll
    for (int k = 0; k < 50; ++k) {
        const float xk = x[k];
#pragma unroll
        for (int j = 0; j < 50; ++j) h[j] = fmaf(xk, W1[k * 50 + j], h[j]);
    }
    float o = b2[0];
#pragma unroll
    for (int j = 0; j < 50; ++j) o = fmaf(fmaxf(h[j], 0.f), W2[j], o);
    out[l] = o;
}

// ---------------------------------------------------------------------------
extern "C" void kernel_launch(void* const* d_in, const int* in_sizes, int n_in,
                              void* d_out, int out_size, void* d_ws, size_t ws_size,
                              hipStream_t stream) {
    const float* locs_l = (const float*)d_in[0];
    const float* locs_r = (const float*)d_in[1];
    const float* g1_pos = (const float*)d_in[2];
    const float* g1_x   = (const float*)d_in[3];
    const float* g2_pos = (const float*)d_in[4];
    const float* g2_x   = (const float*)d_in[5];
    const float* s1_v   = (const float*)d_in[6];
    const float* s1_x   = (const float*)d_in[7];
    const float* s2_v   = (const float*)d_in[8];
    const float* s2_x   = (const float*)d_in[9];
    const float* W1     = (const float*)d_in[10];
    const float* b1     = (const float*)d_in[11];
    const float* W2     = (const float*)d_in[12];
    const float* b2     = (const float*)d_in[13];
    float* out = (float*)d_out;
    float* ws  = (float*)d_ws;

    const int L = in_sizes[0] / 3;   // 4096
    const int N = in_sizes[2] / 3;   // 40000
    const int T = (N + 31) / 32;     // 32-point tiles (1250, exact)
    const int P = T * 16;            // point pairs

    // ws layout (floats): [pk1s: 256T][pkps: 256T][fpk: 512T][red: 26L][keys: 2L u64]
    const size_t o_pkps = (size_t)256 * T;
    const size_t o_fpk  = (size_t)512 * T;
    const size_t o_red  = (size_t)1024 * T;

    const int CT = 40;                       // tiles per chunk
    const int SC = (T + CT - 1) / CT;        // 32 chunks -> grid 32 x 32 x 2

    float4* pk1s = (float4*)ws;
    float4* pkps = (float4*)(ws + o_pkps);
    int4*   fpk  = (int4*)(ws + o_fpk);
    float*  red  = ws + o_red;
    unsigned long long* keys = (unsigned long long*)(red + (size_t)26 * L);

    const int ptasks = 192 * T;              // 4P + 128T, P = 16T  (> 28L)
    pip_pack<<<dim3((ptasks + BLK - 1) / BLK), dim3(BLK), 0, stream>>>(
        g1_pos, g2_pos, s1_v, s1_x, s2_v, s2_x, pk1s, pkps, fpk, red, keys, N, T, L);

    pip_partial<<<dim3(L / 128, SC, 2), dim3(128), 0, stream>>>(
        locs_l, locs_r, pk1s, pkps, fpk, red, keys, L, T, CT, P);

    pip_final<<<dim3((L + BLK - 1) / BLK), dim3(BLK), 0, stream>>>(
        red, keys, g1_x, g2_x, W1, b1, W2, b2, out, L);
}